// Round 2
// baseline (86.763 us; speedup 1.0000x reference)
//
#include <hip/hip_runtime.h>
#include <math.h>

#define C 256
#define H 40
#define W 40
#define NROI 64
#define PH 7
#define PW 7
#define HW (H * W)
#define NBIN (PH * PW)

// ---------------- Kernel 1: transpose (blk 0-99) + saliency (blk 100-124) ----
// v3: saliency moved OFF the transpose blocks into 25 dedicated blocks so the
// two phases run in parallel (prep wall = max, not sum). Transpose globals are
// float4 both directions (1KB/wave-instr); tile stride 65 => 2-way bank
// aliasing (free, m136) in both phases. Saliency keeps the EXACT fp add order
// of the previous kernel (q-group of 64 sequential channels) so absmax is
// unchanged; full unroll only deepens the load pipeline (1 round-trip vs 8).
// Poison/idempotency story unchanged: sal overwritten every launch; smax via
// signed atomicMax over positive floats beats the negative 0xAAAAAAAA poison.
// NOTE (r7 lesson, prior session): do NOT fuse prep+pool with a flag
// handshake — measured +112 us of spin-wait vs ~6 us for the node boundary.
__global__ __launch_bounds__(256) void prep_kernel(
    const float* __restrict__ fm, float* __restrict__ fmT,
    float* __restrict__ sal, int* __restrict__ smax_bits) {
  int blk = blockIdx.x;
  int tid = threadIdx.x;
  if (blk < 100) {  // block-uniform branch: __syncthreads inside is safe
    __shared__ float tile[64][65];  // stride 65: 2-way banks both phases
    int pt = blk >> 2, cy = blk & 3;
    int p0 = pt * 64, c0 = cy * 64;
    const float4* fm4 = (const float4*)fm;
    float4* fmT4 = (float4*)fmT;
    // phase A: fm float4 (4 consecutive pixels) -> tile. lanes vary f ->
    // 16 lanes x 16B = 256B contiguous per channel-row, 4 rows/wave = 1KB.
#pragma unroll
    for (int i = 0; i < 4; ++i) {
      int idx = i * 256 + tid;
      int f = idx & 15;   // which float4 within the 64-pixel span
      int cl = idx >> 4;  // channel 0..63
      float4 v = fm4[(c0 + cl) * (HW / 4) + (p0 >> 2) + f];
      tile[4 * f + 0][cl] = v.x;
      tile[4 * f + 1][cl] = v.y;
      tile[4 * f + 2][cl] = v.z;
      tile[4 * f + 3][cl] = v.w;
    }
    __syncthreads();
    // phase B: tile -> fmT float4 (4 consecutive channels). lanes vary cf.
#pragma unroll
    for (int i = 0; i < 4; ++i) {
      int idx = i * 256 + tid;
      int cf = idx & 15;  // which float4 within the 64-channel span
      int pl = idx >> 4;  // pixel 0..63
      float4 u;
      u.x = tile[pl][4 * cf + 0];
      u.y = tile[pl][4 * cf + 1];
      u.z = tile[pl][4 * cf + 2];
      u.w = tile[pl][4 * cf + 3];
      fmT4[(p0 + pl) * (C / 4) + (c0 >> 2) + cf] = u;
    }
  } else {
    __shared__ float part[4][64];
    int p0 = (blk - 100) * 64;
    int pl = tid & 63, q = tid >> 6;
    float acc = 0.0f;
#pragma unroll
    for (int i = 0; i < 64; ++i) acc += fm[(q * 64 + i) * HW + p0 + pl];
    part[q][pl] = acc;
    __syncthreads();
    if (tid < 64) {
      float s = part[0][tid] + part[1][tid] + part[2][tid] + part[3][tid];
      sal[p0 + tid] = s;
      float m = s;
#pragma unroll
      for (int off = 32; off > 0; off >>= 1) m = fmaxf(m, __shfl_down(m, off));
      if (tid == 0) atomicMax(smax_bits, __float_as_int(m));
    }
  }
}

// ---------------- Kernel 2: pool. wave = (roi, bin); lane = 4 channels -------
// grid 64 x 13 blocks; block 256 thr = 4 waves = 4 bins.
// v2: all <=7 column loads per row issued independently (clamped duplicate
// columns are max-idempotent L1 hits); per-column inside-x tests hoisted.
// v3: 2-row software pipeline — issue row y+1's loads before consuming row y,
// hiding per-row L2 latency on the (up to 7-row) serial row chain.
__global__ __launch_bounds__(256) void pool_kernel(
    const float4* __restrict__ fmT4, const float* __restrict__ rois1,
    const float* __restrict__ rois2, const float* __restrict__ sal,
    const int* __restrict__ smax_bits, float* __restrict__ out) {
  int blk = blockIdx.x;
  int n = blk / 13;
  int g = blk - n * 13;
  int w = threadIdx.x >> 6;
  int l = threadIdx.x & 63;
  int b = g * 4 + w;
  if (b >= NBIN) return;  // whole-wave exit; no barriers below

  const float* r1 = rois1 + n * 5;
  const float* r2 = rois2 + n * 5;
  // jnp.round = round-half-to-even = rintf under default rounding mode.
  int x1a = min((int)rintf(r1[1] * 0.0625f), W - 1);
  int y1a = min((int)rintf(r1[2] * 0.0625f), H - 1);
  int x2a = min((int)rintf(r1[3] * 0.0625f), W - 1);
  int y2a = min((int)rintf(r1[4] * 0.0625f), H - 1);
  int x1b = min((int)rintf(r2[1] * 0.0625f), W - 1);
  int y1b = min((int)rintf(r2[2] * 0.0625f), H - 1);
  int x2b = min((int)rintf(r2[3] * 0.0625f), W - 1);
  int y2b = min((int)rintf(r2[4] * 0.0625f), H - 1);

  int ux1 = min(x1a, x1b), uy1 = min(y1a, y1b);
  int ux2 = max(x2a, x2b), uy2 = max(y2a, y2b);
  int hb = uy2 - uy1 + 1, wb = ux2 - ux1 + 1;

  int ph = b / PW, pw = b - (b / PW) * PW;
  int ys0 = uy1 + (ph * hb) / PH;
  int ys1 = uy1 + ((ph + 1) * hb + PH - 1) / PH;
  int xs0 = ux1 + (pw * wb) / PW;
  int xs1 = ux1 + ((pw + 1) * wb + PW - 1) / PW;
  // bin is never empty: ys1 > ys0, xs1 > xs0. Bin width/height <= 7.

  float inv = 1.0f / __int_as_float(*smax_bits);

  int xl = xs1 - 1;  // last valid column; clamped dups are max-idempotent
  int xc0 = xs0;
  int xc1 = min(xs0 + 1, xl);
  int xc2 = min(xs0 + 2, xl);
  int xc3 = min(xs0 + 3, xl);
  int xc4 = min(xs0 + 4, xl);
  int xc5 = min(xs0 + 5, xl);
  int xc6 = min(xs0 + 6, xl);
  // per-column float4-element offsets (row base added per row)
  int a0 = xc0 * 64 + l, a1 = xc1 * 64 + l, a2 = xc2 * 64 + l;
  int a3 = xc3 * 64 + l, a4 = xc4 * 64 + l, a5 = xc5 * 64 + l;
  int a6 = xc6 * 64 + l;
  // per-column inside-x tests, hoisted out of the row loop
  bool cxa0 = (xc0 >= x1a) & (xc0 <= x2a), cxb0 = (xc0 >= x1b) & (xc0 <= x2b);
  bool cxa1 = (xc1 >= x1a) & (xc1 <= x2a), cxb1 = (xc1 >= x1b) & (xc1 <= x2b);
  bool cxa2 = (xc2 >= x1a) & (xc2 <= x2a), cxb2 = (xc2 >= x1b) & (xc2 <= x2b);
  bool cxa3 = (xc3 >= x1a) & (xc3 <= x2a), cxb3 = (xc3 >= x1b) & (xc3 <= x2b);
  bool cxa4 = (xc4 >= x1a) & (xc4 <= x2a), cxb4 = (xc4 >= x1b) & (xc4 <= x2b);
  bool cxa5 = (xc5 >= x1a) & (xc5 <= x2a), cxb5 = (xc5 >= x1b) & (xc5 <= x2b);
  bool cxa6 = (xc6 >= x1a) & (xc6 <= x2a), cxb6 = (xc6 >= x1b) & (xc6 <= x2b);

  float4 best = make_float4(-INFINITY, -INFINITY, -INFINITY, -INFINITY);

  int y = ys0;
  bool iya = (y >= y1a) & (y <= y2a);
  bool iyb = (y >= y1b) & (y <= y2b);
  int rb = y * W, rb64 = rb * 64;
  float4 v0 = fmT4[rb64 + a0];
  float4 v1 = fmT4[rb64 + a1];
  float4 v2 = fmT4[rb64 + a2];
  float4 v3 = fmT4[rb64 + a3];
  float4 v4 = fmT4[rb64 + a4];
  float4 v5 = fmT4[rb64 + a5];
  float4 v6 = fmT4[rb64 + a6];
  float s0 = sal[rb + xc0];
  float s1 = sal[rb + xc1];
  float s2 = sal[rb + xc2];
  float s3 = sal[rb + xc3];
  float s4 = sal[rb + xc4];
  float s5 = sal[rb + xc5];
  float s6 = sal[rb + xc6];

#define UPD(K)                                                         \
  {                                                                    \
    bool ins = (iya & cxa##K) | (iyb & cxb##K);                        \
    float qq = s##K * inv;                                             \
    qq = qq * qq;                                                      \
    qq = qq * qq;                                                      \
    float m = ins ? 1.0f : fmaf(0.4f, qq, 0.5f);                       \
    best.x = fmaxf(best.x, v##K.x * m);                                \
    best.y = fmaxf(best.y, v##K.y * m);                                \
    best.z = fmaxf(best.z, v##K.z * m);                                \
    best.w = fmaxf(best.w, v##K.w * m);                                \
  }

  for (; y < ys1 - 1; ++y) {
    // issue next row's loads first (2-row pipeline)
    int rbn = (y + 1) * W, rbn64 = rbn * 64;
    float4 w0 = fmT4[rbn64 + a0];
    float4 w1 = fmT4[rbn64 + a1];
    float4 w2 = fmT4[rbn64 + a2];
    float4 w3 = fmT4[rbn64 + a3];
    float4 w4 = fmT4[rbn64 + a4];
    float4 w5 = fmT4[rbn64 + a5];
    float4 w6 = fmT4[rbn64 + a6];
    float t0 = sal[rbn + xc0];
    float t1 = sal[rbn + xc1];
    float t2 = sal[rbn + xc2];
    float t3 = sal[rbn + xc3];
    float t4 = sal[rbn + xc4];
    float t5 = sal[rbn + xc5];
    float t6 = sal[rbn + xc6];
    // consume current row
    UPD(0) UPD(1) UPD(2) UPD(3) UPD(4) UPD(5) UPD(6)
    // rotate
    iya = ((y + 1) >= y1a) & ((y + 1) <= y2a);
    iyb = ((y + 1) >= y1b) & ((y + 1) <= y2b);
    v0 = w0; v1 = w1; v2 = w2; v3 = w3; v4 = w4; v5 = w5; v6 = w6;
    s0 = t0; s1 = t1; s2 = t2; s3 = t3; s4 = t4; s5 = t5; s6 = t6;
  }
  // last row
  UPD(0) UPD(1) UPD(2) UPD(3) UPD(4) UPD(5) UPD(6)
#undef UPD

  int obase = (n * C + 4 * l) * NBIN + b;
  out[obase] = best.x;
  out[obase + NBIN] = best.y;
  out[obase + 2 * NBIN] = best.z;
  out[obase + 3 * NBIN] = best.w;
}

extern "C" void kernel_launch(void* const* d_in, const int* in_sizes, int n_in,
                              void* d_out, int out_size, void* d_ws,
                              size_t ws_size, hipStream_t stream) {
  const float* fm = (const float*)d_in[0];
  const float* r1 = (const float*)d_in[1];
  const float* r2 = (const float*)d_in[2];
  float* out = (float*)d_out;

  char* ws = (char*)d_ws;
  float* sal = (float*)ws;                           // 1600 floats @ 0
  int* smax_bits = (int*)(ws + HW * sizeof(float));  // 1 int @ 6400
  float* fmT = (float*)(ws + 16384);                 // HW*C floats, 16B aligned

  prep_kernel<<<125, 256, 0, stream>>>(fm, fmT, sal, smax_bits);
  pool_kernel<<<NROI * 13, 256, 0, stream>>>((const float4*)fmT, r1, r2, sal,
                                             smax_bits, out);
}

// Round 3
// 76.107 us; speedup vs baseline: 1.1400x; 1.1400x over previous
//
#include <hip/hip_runtime.h>
#include <math.h>

#define C 256
#define H 40
#define W 40
#define NROI 64
#define PH 7
#define PW 7
#define HW (H * W)
#define NBIN (PH * PW)

// ---------------- Kernel 1: fused transpose + saliency + smax ----------------
// grid 100 = (pixel-tile pt = blk>>2) x (channel-tile cy = blk&3).
// All blocks: LDS-tiled transpose fm(C,HW) -> fmT(HW,C).
// cy==0 blocks additionally: s[p] = sum_c fm[c][p] for their 64 pixels,
// wave-reduce max, atomicMax into smax_bits. No memset needed: ws poison
// 0xAAAAAAAA is a NEGATIVE int, and s>0 so __float_as_int(s) is positive ->
// signed atomicMax always replaces poison; on fresh (un-poisoned) launches the
// leftover value equals the new smax (fm restored identically) -> idempotent.
// NOTE (r7 lesson): do NOT fuse prep+pool into one kernel with a flag
// handshake — measured +112 us of spin-wait vs ~6 us for the node boundary.
// r2 lesson: v3 (float4 transpose + parallel saliency blocks + 2-row pool
// pipeline) measured 86.8 vs this source's 76.2 — reverted verbatim as a
// cross-session reproducibility probe to establish the noise band.
__global__ __launch_bounds__(256) void prep_kernel(
    const float* __restrict__ fm, float* __restrict__ fmT,
    float* __restrict__ sal, int* __restrict__ smax_bits) {
  __shared__ float tile[64][65];  // +1 pad: conflict-free both phases
  __shared__ float part[4][64];
  int blk = blockIdx.x;
  int pt = blk >> 2;
  int cy = blk & 3;
  int p0 = pt * 64, c0 = cy * 64;
  int tid = threadIdx.x;

#pragma unroll
  for (int it = 0; it < 16; ++it) {
    int idx = it * 256 + tid;
    int cl = idx >> 6;
    int pl = idx & 63;  // lanes vary pixel -> coalesced read
    tile[pl][cl] = fm[(c0 + cl) * HW + p0 + pl];
  }
  __syncthreads();
#pragma unroll
  for (int it = 0; it < 16; ++it) {
    int idx = it * 256 + tid;
    int pl = idx >> 6;
    int cl = idx & 63;  // lanes vary channel -> coalesced write
    fmT[(p0 + pl) * C + c0 + cl] = tile[pl][cl];
  }

  if (cy == 0) {  // block-uniform branch: __syncthreads inside is safe
    int pl = tid & 63, q = tid >> 6;
    float acc = 0.0f;
#pragma unroll 8
    for (int i = 0; i < 64; ++i) acc += fm[(q * 64 + i) * HW + p0 + pl];
    part[q][pl] = acc;
    __syncthreads();
    if (tid < 64) {
      float s = part[0][tid] + part[1][tid] + part[2][tid] + part[3][tid];
      sal[p0 + tid] = s;
      float m = s;
#pragma unroll
      for (int off = 32; off > 0; off >>= 1) m = fmaxf(m, __shfl_down(m, off));
      if (tid == 0) atomicMax(smax_bits, __float_as_int(m));
    }
  }
}

// ---------------- Kernel 2: pool. wave = (roi, bin); lane = 4 channels -------
// grid 64 x 13 blocks; block 256 thr = 4 waves = 4 bins.
// v2 restructure: row loop serial, but all <=7 column loads per row are issued
// INDEPENDENTLY (7-wide MLP) instead of the old 1-deep serial pixel walk.
// Column coords are clamped to the last in-bin column: duplicate loads hit the
// same address (L1 hit, ~free) and contribute an identical value to the max
// reduction (idempotent), so no validity masking is needed. Per-column
// inside-rect tests (x-only) are hoisted out of the row loop.
__global__ __launch_bounds__(256) void pool_kernel(
    const float4* __restrict__ fmT4, const float* __restrict__ rois1,
    const float* __restrict__ rois2, const float* __restrict__ sal,
    const int* __restrict__ smax_bits, float* __restrict__ out) {
  int blk = blockIdx.x;
  int n = blk / 13;
  int g = blk - n * 13;
  int w = threadIdx.x >> 6;
  int l = threadIdx.x & 63;
  int b = g * 4 + w;
  if (b >= NBIN) return;  // whole-wave exit; no barriers below

  const float* r1 = rois1 + n * 5;
  const float* r2 = rois2 + n * 5;
  // jnp.round = round-half-to-even = rintf under default rounding mode.
  int x1a = min((int)rintf(r1[1] * 0.0625f), W - 1);
  int y1a = min((int)rintf(r1[2] * 0.0625f), H - 1);
  int x2a = min((int)rintf(r1[3] * 0.0625f), W - 1);
  int y2a = min((int)rintf(r1[4] * 0.0625f), H - 1);
  int x1b = min((int)rintf(r2[1] * 0.0625f), W - 1);
  int y1b = min((int)rintf(r2[2] * 0.0625f), H - 1);
  int x2b = min((int)rintf(r2[3] * 0.0625f), W - 1);
  int y2b = min((int)rintf(r2[4] * 0.0625f), H - 1);

  int ux1 = min(x1a, x1b), uy1 = min(y1a, y1b);
  int ux2 = max(x2a, x2b), uy2 = max(y2a, y2b);
  int hb = uy2 - uy1 + 1, wb = ux2 - ux1 + 1;

  int ph = b / PW, pw = b - (b / PW) * PW;
  int ys0 = uy1 + (ph * hb) / PH;
  int ys1 = uy1 + ((ph + 1) * hb + PH - 1) / PH;
  int xs0 = ux1 + (pw * wb) / PW;
  int xs1 = ux1 + ((pw + 1) * wb + PW - 1) / PW;
  // bin is never empty: ys1 > ys0, xs1 > xs0. Bin width <= 7 (hb,wb <= 40).

  float inv = 1.0f / __int_as_float(*smax_bits);

  int xl = xs1 - 1;  // last valid column; clamped dups are max-idempotent
  int xc0 = xs0;
  int xc1 = min(xs0 + 1, xl);
  int xc2 = min(xs0 + 2, xl);
  int xc3 = min(xs0 + 3, xl);
  int xc4 = min(xs0 + 4, xl);
  int xc5 = min(xs0 + 5, xl);
  int xc6 = min(xs0 + 6, xl);
  // per-column float4-element offsets (row base added per row)
  int a0 = xc0 * 64 + l, a1 = xc1 * 64 + l, a2 = xc2 * 64 + l;
  int a3 = xc3 * 64 + l, a4 = xc4 * 64 + l, a5 = xc5 * 64 + l;
  int a6 = xc6 * 64 + l;
  // per-column inside-x tests, hoisted out of the row loop
  bool cxa0 = (xc0 >= x1a) & (xc0 <= x2a), cxb0 = (xc0 >= x1b) & (xc0 <= x2b);
  bool cxa1 = (xc1 >= x1a) & (xc1 <= x2a), cxb1 = (xc1 >= x1b) & (xc1 <= x2b);
  bool cxa2 = (xc2 >= x1a) & (xc2 <= x2a), cxb2 = (xc2 >= x1b) & (xc2 <= x2b);
  bool cxa3 = (xc3 >= x1a) & (xc3 <= x2a), cxb3 = (xc3 >= x1b) & (xc3 <= x2b);
  bool cxa4 = (xc4 >= x1a) & (xc4 <= x2a), cxb4 = (xc4 >= x1b) & (xc4 <= x2b);
  bool cxa5 = (xc5 >= x1a) & (xc5 <= x2a), cxb5 = (xc5 >= x1b) & (xc5 <= x2b);
  bool cxa6 = (xc6 >= x1a) & (xc6 <= x2a), cxb6 = (xc6 >= x1b) & (xc6 <= x2b);

  float4 best = make_float4(-INFINITY, -INFINITY, -INFINITY, -INFINITY);

  for (int y = ys0; y < ys1; ++y) {
    bool iya = (y >= y1a) & (y <= y2a);
    bool iyb = (y >= y1b) & (y <= y2b);
    int rb = y * W;
    int rb64 = rb * 64;
    // 7 independent vector loads + 7 uniform sal loads: deep MLP, no serial
    // address chain. Duplicated columns re-hit the same L1 line.
    float4 v0 = fmT4[rb64 + a0];
    float4 v1 = fmT4[rb64 + a1];
    float4 v2 = fmT4[rb64 + a2];
    float4 v3 = fmT4[rb64 + a3];
    float4 v4 = fmT4[rb64 + a4];
    float4 v5 = fmT4[rb64 + a5];
    float4 v6 = fmT4[rb64 + a6];
    float s0 = sal[rb + xc0];
    float s1 = sal[rb + xc1];
    float s2 = sal[rb + xc2];
    float s3 = sal[rb + xc3];
    float s4 = sal[rb + xc4];
    float s5 = sal[rb + xc5];
    float s6 = sal[rb + xc6];

#define UPD(K)                                                         \
  {                                                                    \
    bool ins = (iya & cxa##K) | (iyb & cxb##K);                        \
    float qq = s##K * inv;                                             \
    qq = qq * qq;                                                      \
    qq = qq * qq;                                                      \
    float m = ins ? 1.0f : fmaf(0.4f, qq, 0.5f);                       \
    best.x = fmaxf(best.x, v##K.x * m);                                \
    best.y = fmaxf(best.y, v##K.y * m);                                \
    best.z = fmaxf(best.z, v##K.z * m);                                \
    best.w = fmaxf(best.w, v##K.w * m);                                \
  }
    UPD(0)
    UPD(1)
    UPD(2)
    UPD(3)
    UPD(4)
    UPD(5)
    UPD(6)
#undef UPD
  }

  int obase = (n * C + 4 * l) * NBIN + b;
  out[obase] = best.x;
  out[obase + NBIN] = best.y;
  out[obase + 2 * NBIN] = best.z;
  out[obase + 3 * NBIN] = best.w;
}

extern "C" void kernel_launch(void* const* d_in, const int* in_sizes, int n_in,
                              void* d_out, int out_size, void* d_ws,
                              size_t ws_size, hipStream_t stream) {
  const float* fm = (const float*)d_in[0];
  const float* r1 = (const float*)d_in[1];
  const float* r2 = (const float*)d_in[2];
  float* out = (float*)d_out;

  char* ws = (char*)d_ws;
  float* sal = (float*)ws;                           // 1600 floats @ 0
  int* smax_bits = (int*)(ws + HW * sizeof(float));  // 1 int @ 6400
  float* fmT = (float*)(ws + 16384);                 // HW*C floats, 16B aligned

  prep_kernel<<<100, 256, 0, stream>>>(fm, fmT, sal, smax_bits);
  pool_kernel<<<NROI * 13, 256, 0, stream>>>((const float4*)fmT, r1, r2, sal,
                                             smax_bits, out);
}

// Round 4
// 75.306 us; speedup vs baseline: 1.1521x; 1.0106x over previous
//
#include <hip/hip_runtime.h>
#include <math.h>

#define C 256
#define H 40
#define W 40
#define NROI 64
#define PH 7
#define PW 7
#define HW (H * W)
#define NBIN (PH * PW)

// ---------------- Kernel 1: transpose (blk 0-99) + saliency (blk 100-124) ----
// r4: SINGLE-VARIABLE change vs the 76.1-us r1 baseline: the cy==0 saliency
// work moves to 25 dedicated blocks so transpose and saliency run in
// PARALLEL (prep wall = max, not sum). The transpose loops and the saliency
// loop bodies are byte-identical to r1 (same scalar loads, same unroll-8 FP
// add order -> absmax unchanged). r2 lesson: the v3 bundle (float4 transpose
// + unroll-64 saliency + explicit 2-row pool pipeline) cost +10.6 us REAL
// (reproducibility A/B r1 vs r3: 76.18 vs 76.11, noise ~0.1 us) — so changes
// land one at a time now.
// Poison/idempotency: sal fully overwritten each launch; smax via signed
// atomicMax over positive floats beats the negative 0xAAAAAAAA poison;
// leftover value from a prior launch equals the new smax -> idempotent.
// NOTE (prior-session r7 lesson): do NOT fuse prep+pool with a flag
// handshake — measured +112 us of spin-wait vs ~6 us for the node boundary.
__global__ __launch_bounds__(256) void prep_kernel(
    const float* __restrict__ fm, float* __restrict__ fmT,
    float* __restrict__ sal, int* __restrict__ smax_bits) {
  __shared__ float tile[64][65];  // +1 pad: conflict-free both phases
  __shared__ float part[4][64];
  int blk = blockIdx.x;
  int tid = threadIdx.x;

  if (blk < 100) {  // block-uniform branch: __syncthreads inside is safe
    int pt = blk >> 2;
    int cy = blk & 3;
    int p0 = pt * 64, c0 = cy * 64;
#pragma unroll
    for (int it = 0; it < 16; ++it) {
      int idx = it * 256 + tid;
      int cl = idx >> 6;
      int pl = idx & 63;  // lanes vary pixel -> coalesced read
      tile[pl][cl] = fm[(c0 + cl) * HW + p0 + pl];
    }
    __syncthreads();
#pragma unroll
    for (int it = 0; it < 16; ++it) {
      int idx = it * 256 + tid;
      int pl = idx >> 6;
      int cl = idx & 63;  // lanes vary channel -> coalesced write
      fmT[(p0 + pl) * C + c0 + cl] = tile[pl][cl];
    }
  } else {
    int p0 = (blk - 100) * 64;
    int pl = tid & 63, q = tid >> 6;
    float acc = 0.0f;
#pragma unroll 8
    for (int i = 0; i < 64; ++i) acc += fm[(q * 64 + i) * HW + p0 + pl];
    part[q][pl] = acc;
    __syncthreads();
    if (tid < 64) {
      float s = part[0][tid] + part[1][tid] + part[2][tid] + part[3][tid];
      sal[p0 + tid] = s;
      float m = s;
#pragma unroll
      for (int off = 32; off > 0; off >>= 1) m = fmaxf(m, __shfl_down(m, off));
      if (tid == 0) atomicMax(smax_bits, __float_as_int(m));
    }
  }
}

// ---------------- Kernel 2: pool. wave = (roi, bin); lane = 4 channels -------
// grid 64 x 13 blocks; block 256 thr = 4 waves = 4 bins. VERBATIM r1 pool
// (76.1 us baseline): row loop serial at source level — the compiler already
// software-pipelines it (no barriers, loop-invariant column offsets) — with
// all <=7 column loads per row issued independently. Clamped duplicate
// columns re-hit the same L1 line and are max-idempotent; per-column
// inside-x tests hoisted out of the row loop.
__global__ __launch_bounds__(256) void pool_kernel(
    const float4* __restrict__ fmT4, const float* __restrict__ rois1,
    const float* __restrict__ rois2, const float* __restrict__ sal,
    const int* __restrict__ smax_bits, float* __restrict__ out) {
  int blk = blockIdx.x;
  int n = blk / 13;
  int g = blk - n * 13;
  int w = threadIdx.x >> 6;
  int l = threadIdx.x & 63;
  int b = g * 4 + w;
  if (b >= NBIN) return;  // whole-wave exit; no barriers below

  const float* r1 = rois1 + n * 5;
  const float* r2 = rois2 + n * 5;
  // jnp.round = round-half-to-even = rintf under default rounding mode.
  int x1a = min((int)rintf(r1[1] * 0.0625f), W - 1);
  int y1a = min((int)rintf(r1[2] * 0.0625f), H - 1);
  int x2a = min((int)rintf(r1[3] * 0.0625f), W - 1);
  int y2a = min((int)rintf(r1[4] * 0.0625f), H - 1);
  int x1b = min((int)rintf(r2[1] * 0.0625f), W - 1);
  int y1b = min((int)rintf(r2[2] * 0.0625f), H - 1);
  int x2b = min((int)rintf(r2[3] * 0.0625f), W - 1);
  int y2b = min((int)rintf(r2[4] * 0.0625f), H - 1);

  int ux1 = min(x1a, x1b), uy1 = min(y1a, y1b);
  int ux2 = max(x2a, x2b), uy2 = max(y2a, y2b);
  int hb = uy2 - uy1 + 1, wb = ux2 - ux1 + 1;

  int ph = b / PW, pw = b - (b / PW) * PW;
  int ys0 = uy1 + (ph * hb) / PH;
  int ys1 = uy1 + ((ph + 1) * hb + PH - 1) / PH;
  int xs0 = ux1 + (pw * wb) / PW;
  int xs1 = ux1 + ((pw + 1) * wb + PW - 1) / PW;
  // bin is never empty: ys1 > ys0, xs1 > xs0. Bin width <= 7 (hb,wb <= 40).

  float inv = 1.0f / __int_as_float(*smax_bits);

  int xl = xs1 - 1;  // last valid column; clamped dups are max-idempotent
  int xc0 = xs0;
  int xc1 = min(xs0 + 1, xl);
  int xc2 = min(xs0 + 2, xl);
  int xc3 = min(xs0 + 3, xl);
  int xc4 = min(xs0 + 4, xl);
  int xc5 = min(xs0 + 5, xl);
  int xc6 = min(xs0 + 6, xl);
  // per-column float4-element offsets (row base added per row)
  int a0 = xc0 * 64 + l, a1 = xc1 * 64 + l, a2 = xc2 * 64 + l;
  int a3 = xc3 * 64 + l, a4 = xc4 * 64 + l, a5 = xc5 * 64 + l;
  int a6 = xc6 * 64 + l;
  // per-column inside-x tests, hoisted out of the row loop
  bool cxa0 = (xc0 >= x1a) & (xc0 <= x2a), cxb0 = (xc0 >= x1b) & (xc0 <= x2b);
  bool cxa1 = (xc1 >= x1a) & (xc1 <= x2a), cxb1 = (xc1 >= x1b) & (xc1 <= x2b);
  bool cxa2 = (xc2 >= x1a) & (xc2 <= x2a), cxb2 = (xc2 >= x1b) & (xc2 <= x2b);
  bool cxa3 = (xc3 >= x1a) & (xc3 <= x2a), cxb3 = (xc3 >= x1b) & (xc3 <= x2b);
  bool cxa4 = (xc4 >= x1a) & (xc4 <= x2a), cxb4 = (xc4 >= x1b) & (xc4 <= x2b);
  bool cxa5 = (xc5 >= x1a) & (xc5 <= x2a), cxb5 = (xc5 >= x1b) & (xc5 <= x2b);
  bool cxa6 = (xc6 >= x1a) & (xc6 <= x2a), cxb6 = (xc6 >= x1b) & (xc6 <= x2b);

  float4 best = make_float4(-INFINITY, -INFINITY, -INFINITY, -INFINITY);

  for (int y = ys0; y < ys1; ++y) {
    bool iya = (y >= y1a) & (y <= y2a);
    bool iyb = (y >= y1b) & (y <= y2b);
    int rb = y * W;
    int rb64 = rb * 64;
    // 7 independent vector loads + 7 uniform sal loads: deep MLP, no serial
    // address chain. Duplicated columns re-hit the same L1 line.
    float4 v0 = fmT4[rb64 + a0];
    float4 v1 = fmT4[rb64 + a1];
    float4 v2 = fmT4[rb64 + a2];
    float4 v3 = fmT4[rb64 + a3];
    float4 v4 = fmT4[rb64 + a4];
    float4 v5 = fmT4[rb64 + a5];
    float4 v6 = fmT4[rb64 + a6];
    float s0 = sal[rb + xc0];
    float s1 = sal[rb + xc1];
    float s2 = sal[rb + xc2];
    float s3 = sal[rb + xc3];
    float s4 = sal[rb + xc4];
    float s5 = sal[rb + xc5];
    float s6 = sal[rb + xc6];

#define UPD(K)                                                         \
  {                                                                    \
    bool ins = (iya & cxa##K) | (iyb & cxb##K);                        \
    float qq = s##K * inv;                                             \
    qq = qq * qq;                                                      \
    qq = qq * qq;                                                      \
    float m = ins ? 1.0f : fmaf(0.4f, qq, 0.5f);                       \
    best.x = fmaxf(best.x, v##K.x * m);                                \
    best.y = fmaxf(best.y, v##K.y * m);                                \
    best.z = fmaxf(best.z, v##K.z * m);                                \
    best.w = fmaxf(best.w, v##K.w * m);                                \
  }
    UPD(0)
    UPD(1)
    UPD(2)
    UPD(3)
    UPD(4)
    UPD(5)
    UPD(6)
#undef UPD
  }

  int obase = (n * C + 4 * l) * NBIN + b;
  out[obase] = best.x;
  out[obase + NBIN] = best.y;
  out[obase + 2 * NBIN] = best.z;
  out[obase + 3 * NBIN] = best.w;
}

extern "C" void kernel_launch(void* const* d_in, const int* in_sizes, int n_in,
                              void* d_out, int out_size, void* d_ws,
                              size_t ws_size, hipStream_t stream) {
  const float* fm = (const float*)d_in[0];
  const float* r1 = (const float*)d_in[1];
  const float* r2 = (const float*)d_in[2];
  float* out = (float*)d_out;

  char* ws = (char*)d_ws;
  float* sal = (float*)ws;                           // 1600 floats @ 0
  int* smax_bits = (int*)(ws + HW * sizeof(float));  // 1 int @ 6400
  float* fmT = (float*)(ws + 16384);                 // HW*C floats, 16B aligned

  prep_kernel<<<125, 256, 0, stream>>>(fm, fmT, sal, smax_bits);
  pool_kernel<<<NROI * 13, 256, 0, stream>>>((const float4*)fmT, r1, r2, sal,
                                             smax_bits, out);
}

// Round 5
// 74.859 us; speedup vs baseline: 1.1590x; 1.0060x over previous
//
#include <hip/hip_runtime.h>
#include <math.h>

#define C 256
#define H 40
#define W 40
#define NROI 64
#define PH 7
#define PW 7
#define HW (H * W)
#define NBIN (PH * PW)

// ---------------- Kernel 1: transpose (blk 0-99) + saliency (blk 100-124) ----
// r5: SINGLE-VARIABLE change vs the 75.3-us r4 baseline: transpose global
// accesses become float4 both directions (4 rounds of dwordx4 instead of 16
// rounds of dword per direction; identical bytes, 4x fewer instructions).
// Bank audit: phase-A writes tile[4f+k][cl] -> banks (4f+cl+65k)%32 = 32
// banks at 2-way (free, m136); phase-B reads tile[pl][4cf+k] -> same, 2-way.
// Coalescing: 4x256B contiguous per wave instruction both phases.
// Saliency blocks (100-124) and pool are VERBATIM r4. This also completes
// the v3-bundle bisect: r2's +10.6us was {float4 transpose, unroll-64
// saliency, 2-row pool pipeline}; split alone won (r4), so if this round
// regresses, float4-transpose was the regressor, else the pool pipeline was.
// Poison/idempotency: sal fully overwritten each launch; smax via signed
// atomicMax over positive floats beats the negative 0xAAAAAAAA poison.
// NOTE (prior-session lesson): do NOT fuse prep+pool with a flag handshake —
// measured +112 us of spin-wait vs ~6 us for the node boundary.
__global__ __launch_bounds__(256) void prep_kernel(
    const float* __restrict__ fm, float* __restrict__ fmT,
    float* __restrict__ sal, int* __restrict__ smax_bits) {
  __shared__ float tile[64][65];  // stride 65: 2-way banks both phases (free)
  __shared__ float part[4][64];
  int blk = blockIdx.x;
  int tid = threadIdx.x;

  if (blk < 100) {  // block-uniform branch: __syncthreads inside is safe
    int pt = blk >> 2;
    int cy = blk & 3;
    int p0 = pt * 64, c0 = cy * 64;
    const float4* fm4 = (const float4*)fm;
    float4* fmT4 = (float4*)fmT;
    // phase A: fm float4 (4 consecutive pixels) -> tile.
    // per wave: 4 segments of 16 lanes x 16B = 256B contiguous.
#pragma unroll
    for (int i = 0; i < 4; ++i) {
      int idx = i * 256 + tid;
      int f = idx & 15;   // which float4 within the 64-pixel span
      int cl = idx >> 4;  // channel 0..63
      float4 v = fm4[(c0 + cl) * (HW / 4) + (pt << 4) + f];
      tile[4 * f + 0][cl] = v.x;
      tile[4 * f + 1][cl] = v.y;
      tile[4 * f + 2][cl] = v.z;
      tile[4 * f + 3][cl] = v.w;
    }
    __syncthreads();
    // phase B: tile -> fmT float4 (4 consecutive channels).
#pragma unroll
    for (int i = 0; i < 4; ++i) {
      int idx = i * 256 + tid;
      int cf = idx & 15;  // which float4 within the 64-channel span
      int pl = idx >> 4;  // pixel 0..63
      float4 u;
      u.x = tile[pl][4 * cf + 0];
      u.y = tile[pl][4 * cf + 1];
      u.z = tile[pl][4 * cf + 2];
      u.w = tile[pl][4 * cf + 3];
      fmT4[(p0 + pl) * (C / 4) + (cy << 4) + cf] = u;
    }
  } else {
    int p0 = (blk - 100) * 64;
    int pl = tid & 63, q = tid >> 6;
    float acc = 0.0f;
#pragma unroll 8
    for (int i = 0; i < 64; ++i) acc += fm[(q * 64 + i) * HW + p0 + pl];
    part[q][pl] = acc;
    __syncthreads();
    if (tid < 64) {
      float s = part[0][tid] + part[1][tid] + part[2][tid] + part[3][tid];
      sal[p0 + tid] = s;
      float m = s;
#pragma unroll
      for (int off = 32; off > 0; off >>= 1) m = fmaxf(m, __shfl_down(m, off));
      if (tid == 0) atomicMax(smax_bits, __float_as_int(m));
    }
  }
}

// ---------------- Kernel 2: pool. wave = (roi, bin); lane = 4 channels -------
// grid 64 x 13 blocks; block 256 thr = 4 waves = 4 bins. VERBATIM r4 pool
// (75.3 us baseline): row loop serial at source level — the compiler already
// software-pipelines it (no barriers, loop-invariant column offsets) — with
// all <=7 column loads per row issued independently. Clamped duplicate
// columns re-hit the same L1 line and are max-idempotent; per-column
// inside-x tests hoisted out of the row loop.
__global__ __launch_bounds__(256) void pool_kernel(
    const float4* __restrict__ fmT4, const float* __restrict__ rois1,
    const float* __restrict__ rois2, const float* __restrict__ sal,
    const int* __restrict__ smax_bits, float* __restrict__ out) {
  int blk = blockIdx.x;
  int n = blk / 13;
  int g = blk - n * 13;
  int w = threadIdx.x >> 6;
  int l = threadIdx.x & 63;
  int b = g * 4 + w;
  if (b >= NBIN) return;  // whole-wave exit; no barriers below

  const float* r1 = rois1 + n * 5;
  const float* r2 = rois2 + n * 5;
  // jnp.round = round-half-to-even = rintf under default rounding mode.
  int x1a = min((int)rintf(r1[1] * 0.0625f), W - 1);
  int y1a = min((int)rintf(r1[2] * 0.0625f), H - 1);
  int x2a = min((int)rintf(r1[3] * 0.0625f), W - 1);
  int y2a = min((int)rintf(r1[4] * 0.0625f), H - 1);
  int x1b = min((int)rintf(r2[1] * 0.0625f), W - 1);
  int y1b = min((int)rintf(r2[2] * 0.0625f), H - 1);
  int x2b = min((int)rintf(r2[3] * 0.0625f), W - 1);
  int y2b = min((int)rintf(r2[4] * 0.0625f), H - 1);

  int ux1 = min(x1a, x1b), uy1 = min(y1a, y1b);
  int ux2 = max(x2a, x2b), uy2 = max(y2a, y2b);
  int hb = uy2 - uy1 + 1, wb = ux2 - ux1 + 1;

  int ph = b / PW, pw = b - (b / PW) * PW;
  int ys0 = uy1 + (ph * hb) / PH;
  int ys1 = uy1 + ((ph + 1) * hb + PH - 1) / PH;
  int xs0 = ux1 + (pw * wb) / PW;
  int xs1 = ux1 + ((pw + 1) * wb + PW - 1) / PW;
  // bin is never empty: ys1 > ys0, xs1 > xs0. Bin width <= 7 (hb,wb <= 40).

  float inv = 1.0f / __int_as_float(*smax_bits);

  int xl = xs1 - 1;  // last valid column; clamped dups are max-idempotent
  int xc0 = xs0;
  int xc1 = min(xs0 + 1, xl);
  int xc2 = min(xs0 + 2, xl);
  int xc3 = min(xs0 + 3, xl);
  int xc4 = min(xs0 + 4, xl);
  int xc5 = min(xs0 + 5, xl);
  int xc6 = min(xs0 + 6, xl);
  // per-column float4-element offsets (row base added per row)
  int a0 = xc0 * 64 + l, a1 = xc1 * 64 + l, a2 = xc2 * 64 + l;
  int a3 = xc3 * 64 + l, a4 = xc4 * 64 + l, a5 = xc5 * 64 + l;
  int a6 = xc6 * 64 + l;
  // per-column inside-x tests, hoisted out of the row loop
  bool cxa0 = (xc0 >= x1a) & (xc0 <= x2a), cxb0 = (xc0 >= x1b) & (xc0 <= x2b);
  bool cxa1 = (xc1 >= x1a) & (xc1 <= x2a), cxb1 = (xc1 >= x1b) & (xc1 <= x2b);
  bool cxa2 = (xc2 >= x1a) & (xc2 <= x2a), cxb2 = (xc2 >= x1b) & (xc2 <= x2b);
  bool cxa3 = (xc3 >= x1a) & (xc3 <= x2a), cxb3 = (xc3 >= x1b) & (xc3 <= x2b);
  bool cxa4 = (xc4 >= x1a) & (xc4 <= x2a), cxb4 = (xc4 >= x1b) & (xc4 <= x2b);
  bool cxa5 = (xc5 >= x1a) & (xc5 <= x2a), cxb5 = (xc5 >= x1b) & (xc5 <= x2b);
  bool cxa6 = (xc6 >= x1a) & (xc6 <= x2a), cxb6 = (xc6 >= x1b) & (xc6 <= x2b);

  float4 best = make_float4(-INFINITY, -INFINITY, -INFINITY, -INFINITY);

  for (int y = ys0; y < ys1; ++y) {
    bool iya = (y >= y1a) & (y <= y2a);
    bool iyb = (y >= y1b) & (y <= y2b);
    int rb = y * W;
    int rb64 = rb * 64;
    // 7 independent vector loads + 7 uniform sal loads: deep MLP, no serial
    // address chain. Duplicated columns re-hit the same L1 line.
    float4 v0 = fmT4[rb64 + a0];
    float4 v1 = fmT4[rb64 + a1];
    float4 v2 = fmT4[rb64 + a2];
    float4 v3 = fmT4[rb64 + a3];
    float4 v4 = fmT4[rb64 + a4];
    float4 v5 = fmT4[rb64 + a5];
    float4 v6 = fmT4[rb64 + a6];
    float s0 = sal[rb + xc0];
    float s1 = sal[rb + xc1];
    float s2 = sal[rb + xc2];
    float s3 = sal[rb + xc3];
    float s4 = sal[rb + xc4];
    float s5 = sal[rb + xc5];
    float s6 = sal[rb + xc6];

#define UPD(K)                                                         \
  {                                                                    \
    bool ins = (iya & cxa##K) | (iyb & cxb##K);                        \
    float qq = s##K * inv;                                             \
    qq = qq * qq;                                                      \
    qq = qq * qq;                                                      \
    float m = ins ? 1.0f : fmaf(0.4f, qq, 0.5f);                       \
    best.x = fmaxf(best.x, v##K.x * m);                                \
    best.y = fmaxf(best.y, v##K.y * m);                                \
    best.z = fmaxf(best.z, v##K.z * m);                                \
    best.w = fmaxf(best.w, v##K.w * m);                                \
  }
    UPD(0)
    UPD(1)
    UPD(2)
    UPD(3)
    UPD(4)
    UPD(5)
    UPD(6)
#undef UPD
  }

  int obase = (n * C + 4 * l) * NBIN + b;
  out[obase] = best.x;
  out[obase + NBIN] = best.y;
  out[obase + 2 * NBIN] = best.z;
  out[obase + 3 * NBIN] = best.w;
}

extern "C" void kernel_launch(void* const* d_in, const int* in_sizes, int n_in,
                              void* d_out, int out_size, void* d_ws,
                              size_t ws_size, hipStream_t stream) {
  const float* fm = (const float*)d_in[0];
  const float* r1 = (const float*)d_in[1];
  const float* r2 = (const float*)d_in[2];
  float* out = (float*)d_out;

  char* ws = (char*)d_ws;
  float* sal = (float*)ws;                           // 1600 floats @ 0
  int* smax_bits = (int*)(ws + HW * sizeof(float));  // 1 int @ 6400
  float* fmT = (float*)(ws + 16384);                 // HW*C floats, 16B aligned

  prep_kernel<<<125, 256, 0, stream>>>(fm, fmT, sal, smax_bits);
  pool_kernel<<<NROI * 13, 256, 0, stream>>>((const float4*)fmT, r1, r2, sal,
                                             smax_bits, out);
}

// Round 6
// 73.278 us; speedup vs baseline: 1.1840x; 1.0216x over previous
//
#include <hip/hip_runtime.h>
#include <math.h>

#define C 256
#define H 40
#define W 40
#define NROI 64
#define PH 7
#define PW 7
#define HW (H * W)
#define NBIN (PH * PW)

// ---------------- Kernel 1: transpose (blk 0-99) + saliency (blk 100-124) ----
// VERBATIM r5 (74.9 us baseline). float4 transpose both directions; saliency
// on 25 dedicated blocks (parallel with transpose, bit-identical FP order).
// Bank audit: tile stride 65 -> 2-way both phases (free, m136).
// Poison/idempotency: sal fully overwritten each launch; smax via signed
// atomicMax over positive floats beats the negative 0xAAAAAAAA poison.
// LESSONS: (r2) do NOT hand-pipeline the pool row loop / unroll-64 saliency —
// +10.6 us real. (prior session) do NOT fuse prep+pool with a flag handshake —
// +112 us spin-wait vs ~6 us node boundary.
__global__ __launch_bounds__(256) void prep_kernel(
    const float* __restrict__ fm, float* __restrict__ fmT,
    float* __restrict__ sal, int* __restrict__ smax_bits) {
  __shared__ float tile[64][65];  // stride 65: 2-way banks both phases (free)
  __shared__ float part[4][64];
  int blk = blockIdx.x;
  int tid = threadIdx.x;

  if (blk < 100) {  // block-uniform branch: __syncthreads inside is safe
    int pt = blk >> 2;
    int cy = blk & 3;
    int p0 = pt * 64, c0 = cy * 64;
    const float4* fm4 = (const float4*)fm;
    float4* fmT4 = (float4*)fmT;
    // phase A: fm float4 (4 consecutive pixels) -> tile.
    // per wave: 4 segments of 16 lanes x 16B = 256B contiguous.
#pragma unroll
    for (int i = 0; i < 4; ++i) {
      int idx = i * 256 + tid;
      int f = idx & 15;   // which float4 within the 64-pixel span
      int cl = idx >> 4;  // channel 0..63
      float4 v = fm4[(c0 + cl) * (HW / 4) + (pt << 4) + f];
      tile[4 * f + 0][cl] = v.x;
      tile[4 * f + 1][cl] = v.y;
      tile[4 * f + 2][cl] = v.z;
      tile[4 * f + 3][cl] = v.w;
    }
    __syncthreads();
    // phase B: tile -> fmT float4 (4 consecutive channels).
#pragma unroll
    for (int i = 0; i < 4; ++i) {
      int idx = i * 256 + tid;
      int cf = idx & 15;  // which float4 within the 64-channel span
      int pl = idx >> 4;  // pixel 0..63
      float4 u;
      u.x = tile[pl][4 * cf + 0];
      u.y = tile[pl][4 * cf + 1];
      u.z = tile[pl][4 * cf + 2];
      u.w = tile[pl][4 * cf + 3];
      fmT4[(p0 + pl) * (C / 4) + (cy << 4) + cf] = u;
    }
  } else {
    int p0 = (blk - 100) * 64;
    int pl = tid & 63, q = tid >> 6;
    float acc = 0.0f;
#pragma unroll 8
    for (int i = 0; i < 64; ++i) acc += fm[(q * 64 + i) * HW + p0 + pl];
    part[q][pl] = acc;
    __syncthreads();
    if (tid < 64) {
      float s = part[0][tid] + part[1][tid] + part[2][tid] + part[3][tid];
      sal[p0 + tid] = s;
      float m = s;
#pragma unroll
      for (int off = 32; off > 0; off >>= 1) m = fmaxf(m, __shfl_down(m, off));
      if (tid == 0) atomicMax(smax_bits, __float_as_int(m));
    }
  }
}

// ---------------- Kernel 2: pool. wave = (roi, bin); lane = 4 channels -------
// grid 64 x 13 blocks; block 256 thr = 4 waves = 4 bins. Compute loop is
// VERBATIM r4/r5 (compiler-pipelined 7-wide row loads; clamped duplicate
// columns are max-idempotent L1 hits; per-column inside-x tests hoisted).
// r6 SINGLE-VARIABLE change: LDS-staged store phase. Before: each thread made
// 4 stores at 784B lane stride -> 64 line-touches of 4B per store instr
// (1024 scattered transactions/block). Now: results staged in stage[256][5]
// (pad 5: write side <=8-way once, read side conflict-free), then lanes
// 4c..4c+3 write 4 consecutive dwords of one 64B line -> coalescer merges to
// 64 line-touches/wave, no 16B-alignment assumption (out rows are 196B, so
// real float4 stores would be misaligned). Early-return replaced by
// predication so all threads reach the barrier legally.
__global__ __launch_bounds__(256) void pool_kernel(
    const float4* __restrict__ fmT4, const float* __restrict__ rois1,
    const float* __restrict__ rois2, const float* __restrict__ sal,
    const int* __restrict__ smax_bits, float* __restrict__ out) {
  __shared__ float stage[256][5];  // [channel][bin-local], pad 5
  int blk = blockIdx.x;
  int n = blk / 13;
  int g = blk - n * 13;
  int w = threadIdx.x >> 6;
  int l = threadIdx.x & 63;
  int b = g * 4 + w;

  if (b < NBIN) {  // wave-uniform predicate (replaces early return)
    const float* r1 = rois1 + n * 5;
    const float* r2 = rois2 + n * 5;
    // jnp.round = round-half-to-even = rintf under default rounding mode.
    int x1a = min((int)rintf(r1[1] * 0.0625f), W - 1);
    int y1a = min((int)rintf(r1[2] * 0.0625f), H - 1);
    int x2a = min((int)rintf(r1[3] * 0.0625f), W - 1);
    int y2a = min((int)rintf(r1[4] * 0.0625f), H - 1);
    int x1b = min((int)rintf(r2[1] * 0.0625f), W - 1);
    int y1b = min((int)rintf(r2[2] * 0.0625f), H - 1);
    int x2b = min((int)rintf(r2[3] * 0.0625f), W - 1);
    int y2b = min((int)rintf(r2[4] * 0.0625f), H - 1);

    int ux1 = min(x1a, x1b), uy1 = min(y1a, y1b);
    int ux2 = max(x2a, x2b), uy2 = max(y2a, y2b);
    int hb = uy2 - uy1 + 1, wb = ux2 - ux1 + 1;

    int ph = b / PW, pw = b - (b / PW) * PW;
    int ys0 = uy1 + (ph * hb) / PH;
    int ys1 = uy1 + ((ph + 1) * hb + PH - 1) / PH;
    int xs0 = ux1 + (pw * wb) / PW;
    int xs1 = ux1 + ((pw + 1) * wb + PW - 1) / PW;
    // bin is never empty: ys1 > ys0, xs1 > xs0. Bin width <= 7.

    float inv = 1.0f / __int_as_float(*smax_bits);

    int xl = xs1 - 1;  // last valid column; clamped dups are max-idempotent
    int xc0 = xs0;
    int xc1 = min(xs0 + 1, xl);
    int xc2 = min(xs0 + 2, xl);
    int xc3 = min(xs0 + 3, xl);
    int xc4 = min(xs0 + 4, xl);
    int xc5 = min(xs0 + 5, xl);
    int xc6 = min(xs0 + 6, xl);
    // per-column float4-element offsets (row base added per row)
    int a0 = xc0 * 64 + l, a1 = xc1 * 64 + l, a2 = xc2 * 64 + l;
    int a3 = xc3 * 64 + l, a4 = xc4 * 64 + l, a5 = xc5 * 64 + l;
    int a6 = xc6 * 64 + l;
    // per-column inside-x tests, hoisted out of the row loop
    bool cxa0 = (xc0 >= x1a) & (xc0 <= x2a), cxb0 = (xc0 >= x1b) & (xc0 <= x2b);
    bool cxa1 = (xc1 >= x1a) & (xc1 <= x2a), cxb1 = (xc1 >= x1b) & (xc1 <= x2b);
    bool cxa2 = (xc2 >= x1a) & (xc2 <= x2a), cxb2 = (xc2 >= x1b) & (xc2 <= x2b);
    bool cxa3 = (xc3 >= x1a) & (xc3 <= x2a), cxb3 = (xc3 >= x1b) & (xc3 <= x2b);
    bool cxa4 = (xc4 >= x1a) & (xc4 <= x2a), cxb4 = (xc4 >= x1b) & (xc4 <= x2b);
    bool cxa5 = (xc5 >= x1a) & (xc5 <= x2a), cxb5 = (xc5 >= x1b) & (xc5 <= x2b);
    bool cxa6 = (xc6 >= x1a) & (xc6 <= x2a), cxb6 = (xc6 >= x1b) & (xc6 <= x2b);

    float4 best = make_float4(-INFINITY, -INFINITY, -INFINITY, -INFINITY);

    for (int y = ys0; y < ys1; ++y) {
      bool iya = (y >= y1a) & (y <= y2a);
      bool iyb = (y >= y1b) & (y <= y2b);
      int rb = y * W;
      int rb64 = rb * 64;
      // 7 independent vector loads + 7 uniform sal loads: deep MLP, no
      // serial address chain. Duplicated columns re-hit the same L1 line.
      float4 v0 = fmT4[rb64 + a0];
      float4 v1 = fmT4[rb64 + a1];
      float4 v2 = fmT4[rb64 + a2];
      float4 v3 = fmT4[rb64 + a3];
      float4 v4 = fmT4[rb64 + a4];
      float4 v5 = fmT4[rb64 + a5];
      float4 v6 = fmT4[rb64 + a6];
      float s0 = sal[rb + xc0];
      float s1 = sal[rb + xc1];
      float s2 = sal[rb + xc2];
      float s3 = sal[rb + xc3];
      float s4 = sal[rb + xc4];
      float s5 = sal[rb + xc5];
      float s6 = sal[rb + xc6];

#define UPD(K)                                                         \
  {                                                                    \
    bool ins = (iya & cxa##K) | (iyb & cxb##K);                        \
    float qq = s##K * inv;                                             \
    qq = qq * qq;                                                      \
    qq = qq * qq;                                                      \
    float m = ins ? 1.0f : fmaf(0.4f, qq, 0.5f);                       \
    best.x = fmaxf(best.x, v##K.x * m);                                \
    best.y = fmaxf(best.y, v##K.y * m);                                \
    best.z = fmaxf(best.z, v##K.z * m);                                \
    best.w = fmaxf(best.w, v##K.w * m);                                \
  }
      UPD(0)
      UPD(1)
      UPD(2)
      UPD(3)
      UPD(4)
      UPD(5)
      UPD(6)
#undef UPD
    }

    // stage results: channel 4l+k, bin-local w
    stage[4 * l + 0][w] = best.x;
    stage[4 * l + 1][w] = best.y;
    stage[4 * l + 2][w] = best.z;
    stage[4 * l + 3][w] = best.w;
  }
  __syncthreads();

  // store phase: enumerate (c, wl) in out-address order so consecutive lanes
  // hit consecutive dwords (4 per 64B line -> wave coalescer merges).
  int tid = threadIdx.x;
#pragma unroll
  for (int j = 0; j < 4; ++j) {
    int idx = j * 256 + tid;
    int c = idx >> 2;
    int wl = idx & 3;
    int bb = 4 * g + wl;
    if (bb < NBIN) out[(n * C + c) * NBIN + bb] = stage[c][wl];
  }
}

extern "C" void kernel_launch(void* const* d_in, const int* in_sizes, int n_in,
                              void* d_out, int out_size, void* d_ws,
                              size_t ws_size, hipStream_t stream) {
  const float* fm = (const float*)d_in[0];
  const float* r1 = (const float*)d_in[1];
  const float* r2 = (const float*)d_in[2];
  float* out = (float*)d_out;

  char* ws = (char*)d_ws;
  float* sal = (float*)ws;                           // 1600 floats @ 0
  int* smax_bits = (int*)(ws + HW * sizeof(float));  // 1 int @ 6400
  float* fmT = (float*)(ws + 16384);                 // HW*C floats, 16B aligned

  prep_kernel<<<125, 256, 0, stream>>>(fm, fmT, sal, smax_bits);
  pool_kernel<<<NROI * 13, 256, 0, stream>>>((const float4*)fmT, r1, r2, sal,
                                             smax_bits, out);
}

// Round 7
// 72.995 us; speedup vs baseline: 1.1886x; 1.0039x over previous
//
#include <hip/hip_runtime.h>
#include <math.h>

#define C 256
#define H 40
#define W 40
#define NROI 64
#define PH 7
#define PW 7
#define HW (H * W)
#define NBIN (PH * PW)

// ---------------- Kernel 1: transpose (blk 0-199) + saliency (blk 200-224) --
// r7 SINGLE-VARIABLE change vs the 73.3-us r6 baseline: transpose tile
// 64x64 -> 32x64 (grid 100 -> 200 transpose blocks, +25 saliency = 225).
// Halves per-block serial depth (2 load + 2 store rounds instead of 4+4)
// and raises CU coverage from ~0.5 to ~0.9 blocks/CU. Coalescing: phase-A
// 8x128B segments/wave; phase-B 4x256B contiguous (same as r5). LDS banks:
// A-writes <=3-way (mild; cost only kicks in >=4-way, m136), B-reads 2-way
// (free). Bit-identical data movement -> absmax unchanged.
// Saliency blocks verbatim (25 blocks, parallel with transpose, bit-identical
// FP order). Poison/idempotency: sal fully overwritten each launch; smax via
// signed atomicMax over positive floats beats the negative 0xAAAAAAAA poison.
// LESSONS: (r2) do NOT hand-pipeline the pool row loop / unroll-64 saliency —
// +10.6 us real. (prior session) do NOT fuse prep+pool with a flag handshake —
// +112 us spin-wait vs ~6 us node boundary.
__global__ __launch_bounds__(256) void prep_kernel(
    const float* __restrict__ fm, float* __restrict__ fmT,
    float* __restrict__ sal, int* __restrict__ smax_bits) {
  __shared__ float tile[32][65];  // 2-way/3-way banks: free-to-mild (m136)
  __shared__ float part[4][64];
  int blk = blockIdx.x;
  int tid = threadIdx.x;

  if (blk < 200) {  // block-uniform branch: __syncthreads inside is safe
    int pt = blk >> 2;
    int cy = blk & 3;
    int p0 = pt * 32, c0 = cy * 64;
    const float4* fm4 = (const float4*)fm;
    float4* fmT4 = (float4*)fmT;
    // phase A: fm float4 (4 consecutive pixels) -> tile. 2 rounds.
    // per wave: 8 channel-rows x 128B contiguous.
#pragma unroll
    for (int i = 0; i < 2; ++i) {
      int idx = i * 256 + tid;
      int f = idx & 7;    // which float4 within the 32-pixel span
      int cl = idx >> 3;  // channel 0..63
      float4 v = fm4[(c0 + cl) * (HW / 4) + (pt << 3) + f];
      tile[4 * f + 0][cl] = v.x;
      tile[4 * f + 1][cl] = v.y;
      tile[4 * f + 2][cl] = v.z;
      tile[4 * f + 3][cl] = v.w;
    }
    __syncthreads();
    // phase B: tile -> fmT float4 (4 consecutive channels). 2 rounds.
    // per wave: 4 pixel-rows x 256B contiguous.
#pragma unroll
    for (int i = 0; i < 2; ++i) {
      int idx = i * 256 + tid;
      int cf = idx & 15;  // which float4 within the 64-channel span
      int pl = idx >> 4;  // pixel 0..31
      float4 u;
      u.x = tile[pl][4 * cf + 0];
      u.y = tile[pl][4 * cf + 1];
      u.z = tile[pl][4 * cf + 2];
      u.w = tile[pl][4 * cf + 3];
      fmT4[(p0 + pl) * (C / 4) + (cy << 4) + cf] = u;
    }
  } else {
    int p0 = (blk - 200) * 64;
    int pl = tid & 63, q = tid >> 6;
    float acc = 0.0f;
#pragma unroll 8
    for (int i = 0; i < 64; ++i) acc += fm[(q * 64 + i) * HW + p0 + pl];
    part[q][pl] = acc;
    __syncthreads();
    if (tid < 64) {
      float s = part[0][tid] + part[1][tid] + part[2][tid] + part[3][tid];
      sal[p0 + tid] = s;
      float m = s;
#pragma unroll
      for (int off = 32; off > 0; off >>= 1) m = fmaxf(m, __shfl_down(m, off));
      if (tid == 0) atomicMax(smax_bits, __float_as_int(m));
    }
  }
}

// ---------------- Kernel 2: pool. wave = (roi, bin); lane = 4 channels -------
// VERBATIM r6 (73.3 us baseline). grid 64 x 13 blocks; block 256 thr = 4
// waves = 4 bins. Compute loop compiler-pipelined (7-wide independent row
// loads; clamped duplicate columns are max-idempotent L1 hits; per-column
// inside-x tests hoisted). Store phase staged through stage[256][5] so lanes
// write consecutive dwords (coalescer merges 4-per-64B-line); out rows are
// 196B so real float4 stores would be misaligned — dword stores by design.
__global__ __launch_bounds__(256) void pool_kernel(
    const float4* __restrict__ fmT4, const float* __restrict__ rois1,
    const float* __restrict__ rois2, const float* __restrict__ sal,
    const int* __restrict__ smax_bits, float* __restrict__ out) {
  __shared__ float stage[256][5];  // [channel][bin-local], pad 5
  int blk = blockIdx.x;
  int n = blk / 13;
  int g = blk - n * 13;
  int w = threadIdx.x >> 6;
  int l = threadIdx.x & 63;
  int b = g * 4 + w;

  if (b < NBIN) {  // wave-uniform predicate (replaces early return)
    const float* r1 = rois1 + n * 5;
    const float* r2 = rois2 + n * 5;
    // jnp.round = round-half-to-even = rintf under default rounding mode.
    int x1a = min((int)rintf(r1[1] * 0.0625f), W - 1);
    int y1a = min((int)rintf(r1[2] * 0.0625f), H - 1);
    int x2a = min((int)rintf(r1[3] * 0.0625f), W - 1);
    int y2a = min((int)rintf(r1[4] * 0.0625f), H - 1);
    int x1b = min((int)rintf(r2[1] * 0.0625f), W - 1);
    int y1b = min((int)rintf(r2[2] * 0.0625f), H - 1);
    int x2b = min((int)rintf(r2[3] * 0.0625f), W - 1);
    int y2b = min((int)rintf(r2[4] * 0.0625f), H - 1);

    int ux1 = min(x1a, x1b), uy1 = min(y1a, y1b);
    int ux2 = max(x2a, x2b), uy2 = max(y2a, y2b);
    int hb = uy2 - uy1 + 1, wb = ux2 - ux1 + 1;

    int ph = b / PW, pw = b - (b / PW) * PW;
    int ys0 = uy1 + (ph * hb) / PH;
    int ys1 = uy1 + ((ph + 1) * hb + PH - 1) / PH;
    int xs0 = ux1 + (pw * wb) / PW;
    int xs1 = ux1 + ((pw + 1) * wb + PW - 1) / PW;
    // bin is never empty: ys1 > ys0, xs1 > xs0. Bin width <= 7.

    float inv = 1.0f / __int_as_float(*smax_bits);

    int xl = xs1 - 1;  // last valid column; clamped dups are max-idempotent
    int xc0 = xs0;
    int xc1 = min(xs0 + 1, xl);
    int xc2 = min(xs0 + 2, xl);
    int xc3 = min(xs0 + 3, xl);
    int xc4 = min(xs0 + 4, xl);
    int xc5 = min(xs0 + 5, xl);
    int xc6 = min(xs0 + 6, xl);
    // per-column float4-element offsets (row base added per row)
    int a0 = xc0 * 64 + l, a1 = xc1 * 64 + l, a2 = xc2 * 64 + l;
    int a3 = xc3 * 64 + l, a4 = xc4 * 64 + l, a5 = xc5 * 64 + l;
    int a6 = xc6 * 64 + l;
    // per-column inside-x tests, hoisted out of the row loop
    bool cxa0 = (xc0 >= x1a) & (xc0 <= x2a), cxb0 = (xc0 >= x1b) & (xc0 <= x2b);
    bool cxa1 = (xc1 >= x1a) & (xc1 <= x2a), cxb1 = (xc1 >= x1b) & (xc1 <= x2b);
    bool cxa2 = (xc2 >= x1a) & (xc2 <= x2a), cxb2 = (xc2 >= x1b) & (xc2 <= x2b);
    bool cxa3 = (xc3 >= x1a) & (xc3 <= x2a), cxb3 = (xc3 >= x1b) & (xc3 <= x2b);
    bool cxa4 = (xc4 >= x1a) & (xc4 <= x2a), cxb4 = (xc4 >= x1b) & (xc4 <= x2b);
    bool cxa5 = (xc5 >= x1a) & (xc5 <= x2a), cxb5 = (xc5 >= x1b) & (xc5 <= x2b);
    bool cxa6 = (xc6 >= x1a) & (xc6 <= x2a), cxb6 = (xc6 >= x1b) & (xc6 <= x2b);

    float4 best = make_float4(-INFINITY, -INFINITY, -INFINITY, -INFINITY);

    for (int y = ys0; y < ys1; ++y) {
      bool iya = (y >= y1a) & (y <= y2a);
      bool iyb = (y >= y1b) & (y <= y2b);
      int rb = y * W;
      int rb64 = rb * 64;
      // 7 independent vector loads + 7 uniform sal loads: deep MLP, no
      // serial address chain. Duplicated columns re-hit the same L1 line.
      float4 v0 = fmT4[rb64 + a0];
      float4 v1 = fmT4[rb64 + a1];
      float4 v2 = fmT4[rb64 + a2];
      float4 v3 = fmT4[rb64 + a3];
      float4 v4 = fmT4[rb64 + a4];
      float4 v5 = fmT4[rb64 + a5];
      float4 v6 = fmT4[rb64 + a6];
      float s0 = sal[rb + xc0];
      float s1 = sal[rb + xc1];
      float s2 = sal[rb + xc2];
      float s3 = sal[rb + xc3];
      float s4 = sal[rb + xc4];
      float s5 = sal[rb + xc5];
      float s6 = sal[rb + xc6];

#define UPD(K)                                                         \
  {                                                                    \
    bool ins = (iya & cxa##K) | (iyb & cxb##K);                        \
    float qq = s##K * inv;                                             \
    qq = qq * qq;                                                      \
    qq = qq * qq;                                                      \
    float m = ins ? 1.0f : fmaf(0.4f, qq, 0.5f);                       \
    best.x = fmaxf(best.x, v##K.x * m);                                \
    best.y = fmaxf(best.y, v##K.y * m);                                \
    best.z = fmaxf(best.z, v##K.z * m);                                \
    best.w = fmaxf(best.w, v##K.w * m);                                \
  }
      UPD(0)
      UPD(1)
      UPD(2)
      UPD(3)
      UPD(4)
      UPD(5)
      UPD(6)
#undef UPD
    }

    // stage results: channel 4l+k, bin-local w
    stage[4 * l + 0][w] = best.x;
    stage[4 * l + 1][w] = best.y;
    stage[4 * l + 2][w] = best.z;
    stage[4 * l + 3][w] = best.w;
  }
  __syncthreads();

  // store phase: enumerate (c, wl) in out-address order so consecutive lanes
  // hit consecutive dwords (4 per 64B line -> wave coalescer merges).
  int tid = threadIdx.x;
#pragma unroll
  for (int j = 0; j < 4; ++j) {
    int idx = j * 256 + tid;
    int c = idx >> 2;
    int wl = idx & 3;
    int bb = 4 * g + wl;
    if (bb < NBIN) out[(n * C + c) * NBIN + bb] = stage[c][wl];
  }
}

extern "C" void kernel_launch(void* const* d_in, const int* in_sizes, int n_in,
                              void* d_out, int out_size, void* d_ws,
                              size_t ws_size, hipStream_t stream) {
  const float* fm = (const float*)d_in[0];
  const float* r1 = (const float*)d_in[1];
  const float* r2 = (const float*)d_in[2];
  float* out = (float*)d_out;

  char* ws = (char*)d_ws;
  float* sal = (float*)ws;                           // 1600 floats @ 0
  int* smax_bits = (int*)(ws + HW * sizeof(float));  // 1 int @ 6400
  float* fmT = (float*)(ws + 16384);                 // HW*C floats, 16B aligned

  prep_kernel<<<225, 256, 0, stream>>>(fm, fmT, sal, smax_bits);
  pool_kernel<<<NROI * 13, 256, 0, stream>>>((const float4*)fmT, r1, r2, sal,
                                             smax_bits, out);
}

// Round 8
// 72.062 us; speedup vs baseline: 1.2040x; 1.0129x over previous
//
#include <hip/hip_runtime.h>
#include <math.h>

#define C 256
#define H 40
#define W 40
#define NROI 64
#define PH 7
#define PW 7
#define HW (H * W)
#define NBIN (PH * PW)

// ---------------- Kernel 1: transpose (blk 0-199) + saliency (blk 200-224) --
// r8 SINGLE-VARIABLE change vs the 73.0-us r7 baseline: saliency unroll
// 8 -> 16 (8 serial load rounds -> 4). With the transpose at 2+2 rounds
// (r7), saliency's 8 rounds were the prep wall. FP add order unchanged
// (same sequential i within q-group) -> absmax unchanged. Only 25 blocks
// affected; +~32 VGPRs there is occupancy-irrelevant (0.9 blocks/CU).
// Transpose blocks verbatim r7: tile 32x64, grid 200, float4 both
// directions, 2-way/3-way LDS banks (free-to-mild, m136).
// Poison/idempotency: sal fully overwritten each launch; smax via signed
// atomicMax over positive floats beats the negative 0xAAAAAAAA poison.
// LESSONS: (r2) do NOT hand-pipeline the pool row loop — +10.6 us real.
// (prior session) do NOT fuse prep+pool with a flag handshake — +112 us.
__global__ __launch_bounds__(256) void prep_kernel(
    const float* __restrict__ fm, float* __restrict__ fmT,
    float* __restrict__ sal, int* __restrict__ smax_bits) {
  __shared__ float tile[32][65];  // 2-way/3-way banks: free-to-mild (m136)
  __shared__ float part[4][64];
  int blk = blockIdx.x;
  int tid = threadIdx.x;

  if (blk < 200) {  // block-uniform branch: __syncthreads inside is safe
    int pt = blk >> 2;
    int cy = blk & 3;
    int p0 = pt * 32, c0 = cy * 64;
    const float4* fm4 = (const float4*)fm;
    float4* fmT4 = (float4*)fmT;
    // phase A: fm float4 (4 consecutive pixels) -> tile. 2 rounds.
    // per wave: 8 channel-rows x 128B contiguous.
#pragma unroll
    for (int i = 0; i < 2; ++i) {
      int idx = i * 256 + tid;
      int f = idx & 7;    // which float4 within the 32-pixel span
      int cl = idx >> 3;  // channel 0..63
      float4 v = fm4[(c0 + cl) * (HW / 4) + (pt << 3) + f];
      tile[4 * f + 0][cl] = v.x;
      tile[4 * f + 1][cl] = v.y;
      tile[4 * f + 2][cl] = v.z;
      tile[4 * f + 3][cl] = v.w;
    }
    __syncthreads();
    // phase B: tile -> fmT float4 (4 consecutive channels). 2 rounds.
    // per wave: 4 pixel-rows x 256B contiguous.
#pragma unroll
    for (int i = 0; i < 2; ++i) {
      int idx = i * 256 + tid;
      int cf = idx & 15;  // which float4 within the 64-channel span
      int pl = idx >> 4;  // pixel 0..31
      float4 u;
      u.x = tile[pl][4 * cf + 0];
      u.y = tile[pl][4 * cf + 1];
      u.z = tile[pl][4 * cf + 2];
      u.w = tile[pl][4 * cf + 3];
      fmT4[(p0 + pl) * (C / 4) + (cy << 4) + cf] = u;
    }
  } else {
    int p0 = (blk - 200) * 64;
    int pl = tid & 63, q = tid >> 6;
    float acc = 0.0f;
#pragma unroll 16
    for (int i = 0; i < 64; ++i) acc += fm[(q * 64 + i) * HW + p0 + pl];
    part[q][pl] = acc;
    __syncthreads();
    if (tid < 64) {
      float s = part[0][tid] + part[1][tid] + part[2][tid] + part[3][tid];
      sal[p0 + tid] = s;
      float m = s;
#pragma unroll
      for (int off = 32; off > 0; off >>= 1) m = fmaxf(m, __shfl_down(m, off));
      if (tid == 0) atomicMax(smax_bits, __float_as_int(m));
    }
  }
}

// ---------------- Kernel 2: pool. wave = (roi, bin); lane = 4 channels -------
// VERBATIM r6/r7 (73.0 us baseline). grid 64 x 13 blocks; block 256 thr = 4
// waves = 4 bins. Compute loop compiler-pipelined (7-wide independent row
// loads; clamped duplicate columns are max-idempotent L1 hits; per-column
// inside-x tests hoisted). Store phase staged through stage[256][5] so lanes
// write consecutive dwords (coalescer merges 4-per-64B-line); out rows are
// 196B so real float4 stores would be misaligned — dword stores by design.
__global__ __launch_bounds__(256) void pool_kernel(
    const float4* __restrict__ fmT4, const float* __restrict__ rois1,
    const float* __restrict__ rois2, const float* __restrict__ sal,
    const int* __restrict__ smax_bits, float* __restrict__ out) {
  __shared__ float stage[256][5];  // [channel][bin-local], pad 5
  int blk = blockIdx.x;
  int n = blk / 13;
  int g = blk - n * 13;
  int w = threadIdx.x >> 6;
  int l = threadIdx.x & 63;
  int b = g * 4 + w;

  if (b < NBIN) {  // wave-uniform predicate (replaces early return)
    const float* r1 = rois1 + n * 5;
    const float* r2 = rois2 + n * 5;
    // jnp.round = round-half-to-even = rintf under default rounding mode.
    int x1a = min((int)rintf(r1[1] * 0.0625f), W - 1);
    int y1a = min((int)rintf(r1[2] * 0.0625f), H - 1);
    int x2a = min((int)rintf(r1[3] * 0.0625f), W - 1);
    int y2a = min((int)rintf(r1[4] * 0.0625f), H - 1);
    int x1b = min((int)rintf(r2[1] * 0.0625f), W - 1);
    int y1b = min((int)rintf(r2[2] * 0.0625f), H - 1);
    int x2b = min((int)rintf(r2[3] * 0.0625f), W - 1);
    int y2b = min((int)rintf(r2[4] * 0.0625f), H - 1);

    int ux1 = min(x1a, x1b), uy1 = min(y1a, y1b);
    int ux2 = max(x2a, x2b), uy2 = max(y2a, y2b);
    int hb = uy2 - uy1 + 1, wb = ux2 - ux1 + 1;

    int ph = b / PW, pw = b - (b / PW) * PW;
    int ys0 = uy1 + (ph * hb) / PH;
    int ys1 = uy1 + ((ph + 1) * hb + PH - 1) / PH;
    int xs0 = ux1 + (pw * wb) / PW;
    int xs1 = ux1 + ((pw + 1) * wb + PW - 1) / PW;
    // bin is never empty: ys1 > ys0, xs1 > xs0. Bin width <= 7.

    float inv = 1.0f / __int_as_float(*smax_bits);

    int xl = xs1 - 1;  // last valid column; clamped dups are max-idempotent
    int xc0 = xs0;
    int xc1 = min(xs0 + 1, xl);
    int xc2 = min(xs0 + 2, xl);
    int xc3 = min(xs0 + 3, xl);
    int xc4 = min(xs0 + 4, xl);
    int xc5 = min(xs0 + 5, xl);
    int xc6 = min(xs0 + 6, xl);
    // per-column float4-element offsets (row base added per row)
    int a0 = xc0 * 64 + l, a1 = xc1 * 64 + l, a2 = xc2 * 64 + l;
    int a3 = xc3 * 64 + l, a4 = xc4 * 64 + l, a5 = xc5 * 64 + l;
    int a6 = xc6 * 64 + l;
    // per-column inside-x tests, hoisted out of the row loop
    bool cxa0 = (xc0 >= x1a) & (xc0 <= x2a), cxb0 = (xc0 >= x1b) & (xc0 <= x2b);
    bool cxa1 = (xc1 >= x1a) & (xc1 <= x2a), cxb1 = (xc1 >= x1b) & (xc1 <= x2b);
    bool cxa2 = (xc2 >= x1a) & (xc2 <= x2a), cxb2 = (xc2 >= x1b) & (xc2 <= x2b);
    bool cxa3 = (xc3 >= x1a) & (xc3 <= x2a), cxb3 = (xc3 >= x1b) & (xc3 <= x2b);
    bool cxa4 = (xc4 >= x1a) & (xc4 <= x2a), cxb4 = (xc4 >= x1b) & (xc4 <= x2b);
    bool cxa5 = (xc5 >= x1a) & (xc5 <= x2a), cxb5 = (xc5 >= x1b) & (xc5 <= x2b);
    bool cxa6 = (xc6 >= x1a) & (xc6 <= x2a), cxb6 = (xc6 >= x1b) & (xc6 <= x2b);

    float4 best = make_float4(-INFINITY, -INFINITY, -INFINITY, -INFINITY);

    for (int y = ys0; y < ys1; ++y) {
      bool iya = (y >= y1a) & (y <= y2a);
      bool iyb = (y >= y1b) & (y <= y2b);
      int rb = y * W;
      int rb64 = rb * 64;
      // 7 independent vector loads + 7 uniform sal loads: deep MLP, no
      // serial address chain. Duplicated columns re-hit the same L1 line.
      float4 v0 = fmT4[rb64 + a0];
      float4 v1 = fmT4[rb64 + a1];
      float4 v2 = fmT4[rb64 + a2];
      float4 v3 = fmT4[rb64 + a3];
      float4 v4 = fmT4[rb64 + a4];
      float4 v5 = fmT4[rb64 + a5];
      float4 v6 = fmT4[rb64 + a6];
      float s0 = sal[rb + xc0];
      float s1 = sal[rb + xc1];
      float s2 = sal[rb + xc2];
      float s3 = sal[rb + xc3];
      float s4 = sal[rb + xc4];
      float s5 = sal[rb + xc5];
      float s6 = sal[rb + xc6];

#define UPD(K)                                                         \
  {                                                                    \
    bool ins = (iya & cxa##K) | (iyb & cxb##K);                        \
    float qq = s##K * inv;                                             \
    qq = qq * qq;                                                      \
    qq = qq * qq;                                                      \
    float m = ins ? 1.0f : fmaf(0.4f, qq, 0.5f);                       \
    best.x = fmaxf(best.x, v##K.x * m);                                \
    best.y = fmaxf(best.y, v##K.y * m);                                \
    best.z = fmaxf(best.z, v##K.z * m);                                \
    best.w = fmaxf(best.w, v##K.w * m);                                \
  }
      UPD(0)
      UPD(1)
      UPD(2)
      UPD(3)
      UPD(4)
      UPD(5)
      UPD(6)
#undef UPD
    }

    // stage results: channel 4l+k, bin-local w
    stage[4 * l + 0][w] = best.x;
    stage[4 * l + 1][w] = best.y;
    stage[4 * l + 2][w] = best.z;
    stage[4 * l + 3][w] = best.w;
  }
  __syncthreads();

  // store phase: enumerate (c, wl) in out-address order so consecutive lanes
  // hit consecutive dwords (4 per 64B line -> wave coalescer merges).
  int tid = threadIdx.x;
#pragma unroll
  for (int j = 0; j < 4; ++j) {
    int idx = j * 256 + tid;
    int c = idx >> 2;
    int wl = idx & 3;
    int bb = 4 * g + wl;
    if (bb < NBIN) out[(n * C + c) * NBIN + bb] = stage[c][wl];
  }
}

extern "C" void kernel_launch(void* const* d_in, const int* in_sizes, int n_in,
                              void* d_out, int out_size, void* d_ws,
                              size_t ws_size, hipStream_t stream) {
  const float* fm = (const float*)d_in[0];
  const float* r1 = (const float*)d_in[1];
  const float* r2 = (const float*)d_in[2];
  float* out = (float*)d_out;

  char* ws = (char*)d_ws;
  float* sal = (float*)ws;                           // 1600 floats @ 0
  int* smax_bits = (int*)(ws + HW * sizeof(float));  // 1 int @ 6400
  float* fmT = (float*)(ws + 16384);                 // HW*C floats, 16B aligned

  prep_kernel<<<225, 256, 0, stream>>>(fm, fmT, sal, smax_bits);
  pool_kernel<<<NROI * 13, 256, 0, stream>>>((const float4*)fmT, r1, r2, sal,
                                             smax_bits, out);
}